// Round 1
// baseline (145.930 us; speedup 1.0000x reference)
//
#include <hip/hip_runtime.h>

#define DEV __device__ __forceinline__

typedef __bf16 bf16x8 __attribute__((ext_vector_type(8)));
typedef float  f32x4  __attribute__((ext_vector_type(4)));

static constexpr float SCALE = 0.036084391824351615f;   // 1/sqrt(768)
static constexpr float L2E   = 1.4426950408889634f;

DEV unsigned short f2bf(float f) {
  return __builtin_bit_cast(unsigned short, (__bf16)f);
}
DEV unsigned int pack2(float a, float b) {
  return (unsigned int)f2bf(a) | ((unsigned int)f2bf(b) << 16);
}

// async global->LDS, 16B per lane. lds ptr must be wave-uniform; HW adds lane*16.
#define GLDS16(gp, lp) \
  __builtin_amdgcn_global_load_lds((__attribute__((address_space(1))) void*)(gp), \
                                   (__attribute__((address_space(3))) void*)(lp), 16, 0, 0)

// ---------------------------------------------------------------- prep kernels

__global__ __launch_bounds__(256) void k_cvt_bf16(const float* __restrict__ in,
                                                  unsigned short* __restrict__ out,
                                                  int n8) {
  int i = blockIdx.x * 256 + threadIdx.x;
  if (i >= n8) return;
  const float4* p = (const float4*)in + (size_t)i * 2;
  float4 a = p[0], b = p[1];
  uint4 r;
  r.x = pack2(a.x, a.y); r.y = pack2(a.z, a.w);
  r.z = pack2(b.x, b.y); r.w = pack2(b.z, b.w);
  ((uint4*)out)[i] = r;
}

// in [R][C] f32 -> out [C][R] bf16. grid (C/64, R/64), 256 threads.
__global__ __launch_bounds__(256) void k_transpose_w(const float* __restrict__ in,
                                                     unsigned short* __restrict__ out,
                                                     int R, int C) {
  __shared__ float tile[64][65];
  int c0 = blockIdx.x * 64, r0 = blockIdx.y * 64;
  int t = threadIdx.x, tr = t >> 6, tc = t & 63;
#pragma unroll
  for (int i = 0; i < 64; i += 4)
    tile[i + tr][tc] = in[(size_t)(r0 + i + tr) * C + c0 + tc];
  __syncthreads();
#pragma unroll
  for (int i = 0; i < 64; i += 4)
    out[(size_t)(c0 + i + tr) * R + r0 + tc] = f2bf(tile[tc][i + tr]);
}

// V [96][1024][64] bf16 -> VT [96][64][1024] bf16. grid = 96*16.
__global__ __launch_bounds__(256) void k_transpose_v(const unsigned short* __restrict__ V,
                                                     unsigned short* __restrict__ VT) {
  __shared__ __align__(16) unsigned short tile[64 * 64];
  int bh = blockIdx.x >> 4, nt = blockIdx.x & 15;
  int t = threadIdx.x;
#pragma unroll
  for (int it = 0; it < 2; ++it) {
    int idx = (it * 256 + t) * 8;
    int n = idx >> 6, d0 = idx & 63;
    uint4 v = *(const uint4*)(V + ((size_t)(bh * 1024 + nt * 64 + n)) * 64 + d0);
    int chunk = (d0 >> 3) ^ (n >> 3);            // XOR swizzle, 16B granules
    *(uint4*)&tile[n * 64 + chunk * 8] = v;
  }
  __syncthreads();
#pragma unroll
  for (int it = 0; it < 2; ++it) {
    int odx = (it * 256 + t) * 8;
    int d = odx >> 6, nc = odx & 63;
    unsigned short r[8];
#pragma unroll
    for (int i = 0; i < 8; ++i) {
      int n = nc + i;
      r[i] = tile[n * 64 + (((d >> 3) ^ (n >> 3)) * 8) + (d & 7)];
    }
    *(uint4*)(VT + ((size_t)(bh * 64 + d)) * 1024 + nt * 64 + nc) = *(uint4*)r;
  }
}

// ---------------------------------------------------------------- GEMM (K=768)
// A [8192][768] bf16, BT [N][768] bf16 (pre-transposed). 128x128 tile, BK=64,
// 4 waves (2x2), each wave 64x64 = 4x4 MFMA 16x16x32 frags.
// MODE 0: N=2304, split into Q(*SCALE)/K/V [b,h,n,d] bf16.
// MODE 1: N=768, out = fp32 + bias.
template <int MODE>
__global__ __launch_bounds__(256) void k_gemm(const unsigned short* __restrict__ A,
                                              const unsigned short* __restrict__ BT,
                                              void* __restrict__ out0,
                                              unsigned short* __restrict__ Kb,
                                              unsigned short* __restrict__ Vb,
                                              const float* __restrict__ bias) {
  __shared__ __align__(16) char smem[32768];
  char* As = smem;
  char* Bs = smem + 16384;
  const int tid = threadIdx.x;
  const int wave = tid >> 6, lane = tid & 63;
  const int g = lane >> 4, l15 = lane & 15;
  const int wrow = wave >> 1, wcol = wave & 1;
  const int bm = blockIdx.y, bn = blockIdx.x;

  f32x4 acc[4][4] = {};
  const unsigned short* Abase = A + (size_t)bm * 128 * 768;
  const unsigned short* Bbase = BT + (size_t)bn * 128 * 768;

  for (int kt = 0; kt < 12; ++kt) {
    const int k0 = kt * 64;
#pragma unroll
    for (int i = 0; i < 4; ++i) {
      int q = i * 256 + tid;
      int row = q >> 3, c = q & 7;
      int cs = c ^ (row & 7);                    // pre-swizzled global source
      GLDS16(Abase + (size_t)row * 768 + k0 + cs * 8, As + (i * 256 + wave * 64) * 16);
      GLDS16(Bbase + (size_t)row * 768 + k0 + cs * 8, Bs + (i * 256 + wave * 64) * 16);
    }
    __syncthreads();
#pragma unroll
    for (int kk = 0; kk < 2; ++kk) {
      bf16x8 af[4], bfr[4];
#pragma unroll
      for (int mi = 0; mi < 4; ++mi) {
        int r = wrow * 64 + mi * 16 + l15;
        af[mi] = *(const bf16x8*)(As + r * 128 + (((kk * 4 + g) ^ (r & 7)) * 16));
      }
#pragma unroll
      for (int ni = 0; ni < 4; ++ni) {
        int r = wcol * 64 + ni * 16 + l15;
        bfr[ni] = *(const bf16x8*)(Bs + r * 128 + (((kk * 4 + g) ^ (r & 7)) * 16));
      }
#pragma unroll
      for (int mi = 0; mi < 4; ++mi)
#pragma unroll
        for (int ni = 0; ni < 4; ++ni)
          acc[mi][ni] = __builtin_amdgcn_mfma_f32_16x16x32_bf16(af[mi], bfr[ni], acc[mi][ni], 0, 0, 0);
    }
    __syncthreads();
  }

  const int row0 = bm * 128 + wrow * 64;
  const int col0 = bn * 128 + wcol * 64;
#pragma unroll
  for (int mi = 0; mi < 4; ++mi) {
#pragma unroll
    for (int ni = 0; ni < 4; ++ni) {
      int col = col0 + ni * 16 + l15;
      if (MODE == 0) {
        int which = col / 768;
        int hd = col - which * 768;
        int head = hd >> 6, d = hd & 63;
        unsigned short* dst = (which == 0) ? (unsigned short*)out0 : (which == 1 ? Kb : Vb);
        float scl = (which == 0) ? SCALE : 1.0f;
#pragma unroll
        for (int j = 0; j < 4; ++j) {
          int rowm = row0 + mi * 16 + g * 4 + j;
          int bi = rowm >> 10, np = rowm & 1023;
          dst[((size_t)(bi * 12 + head) * 1024 + np) * 64 + d] = f2bf(acc[mi][ni][j] * scl);
        }
      } else {
        float bz = bias[col];
#pragma unroll
        for (int j = 0; j < 4; ++j) {
          int rowm = row0 + mi * 16 + g * 4 + j;
          ((float*)out0)[(size_t)rowm * 768 + col] = acc[mi][ni][j] + bz;
        }
      }
    }
  }
}

// ---------------------------------------------------------------- attention
// grid = 96 (b*h) * 8 (q-tiles of 128). 4 waves; each wave owns 32 q-rows.
// Swapped QK^T: st = mfma(K_frag, Q_frag) -> lane-local softmax per q-row.
__global__ __launch_bounds__(256) void k_attn(const unsigned short* __restrict__ Qb,
                                              const unsigned short* __restrict__ Kb,
                                              const unsigned short* __restrict__ VTb,
                                              unsigned short* __restrict__ Ao) {
  __shared__ __align__(16) char smem[32768];   // K 8K | VT 8K | P 4x4K
  char* Ks = smem;
  char* Vs = smem + 8192;
  char* Ps = smem + 16384;
  const int tid = threadIdx.x, wave = tid >> 6, lane = tid & 63;
  const int g = lane >> 4, l15 = lane & 15;
  const int bh = blockIdx.x >> 3, qt = blockIdx.x & 7;
  const int qbase = qt * 128 + wave * 32;
  const size_t qkbase = (size_t)bh * 1024 * 64;

  bf16x8 aq[2][2];
#pragma unroll
  for (int mi = 0; mi < 2; ++mi)
#pragma unroll
    for (int kk = 0; kk < 2; ++kk)
      aq[mi][kk] = *(const bf16x8*)(Qb + qkbase + (size_t)(qbase + mi * 16 + l15) * 64 + kk * 32 + g * 8);

  f32x4 o[2][4] = {};
  float mrow[2] = {-1e30f, -1e30f};
  float lrow[2] = {0.f, 0.f};
  char* Pw = Ps + wave * 4096;

  for (int kt = 0; kt < 16; ++kt) {
#pragma unroll
    for (int i = 0; i < 2; ++i) {
      int q = i * 256 + tid;
      int row = q >> 3, c = q & 7;
      int cs = c ^ (row & 7);
      GLDS16(Kb + qkbase + (size_t)(kt * 64 + row) * 64 + cs * 8, Ks + (i * 256 + wave * 64) * 16);
      GLDS16(VTb + (size_t)bh * 64 * 1024 + (size_t)row * 1024 + kt * 64 + cs * 8,
             Vs + (i * 256 + wave * 64) * 16);
    }
    __syncthreads();

    // S^T tiles: st[qf][kf][j] = S[q = qbase+qf*16+l15][k = kt*64+kf*16+g*4+j]
    f32x4 st[2][4] = {};
#pragma unroll
    for (int dk = 0; dk < 2; ++dk) {
      bf16x8 ka[4];
#pragma unroll
      for (int kf = 0; kf < 4; ++kf) {
        int r = kf * 16 + l15;
        ka[kf] = *(const bf16x8*)(Ks + r * 128 + (((dk * 4 + g) ^ (r & 7)) * 16));
      }
#pragma unroll
      for (int qf = 0; qf < 2; ++qf)
#pragma unroll
        for (int kf = 0; kf < 4; ++kf)
          st[qf][kf] = __builtin_amdgcn_mfma_f32_16x16x32_bf16(ka[kf], aq[qf][dk], st[qf][kf], 0, 0, 0);
    }

#pragma unroll
    for (int qf = 0; qf < 2; ++qf) {
      float mx = -1e30f;
#pragma unroll
      for (int kf = 0; kf < 4; ++kf)
#pragma unroll
        for (int j = 0; j < 4; ++j) mx = fmaxf(mx, st[qf][kf][j]);
      mx = fmaxf(mx, __shfl_xor(mx, 16));
      mx = fmaxf(mx, __shfl_xor(mx, 32));
      float mnew = fmaxf(mrow[qf], mx);
      float alpha = __builtin_amdgcn_exp2f((mrow[qf] - mnew) * L2E);
      mrow[qf] = mnew;
      float sum = 0.f;
#pragma unroll
      for (int kf = 0; kf < 4; ++kf)
#pragma unroll
        for (int j = 0; j < 4; ++j) {
          float e = __builtin_amdgcn_exp2f((st[qf][kf][j] - mnew) * L2E);
          st[qf][kf][j] = e;
          sum += e;
        }
      sum += __shfl_xor(sum, 16);
      sum += __shfl_xor(sum, 32);
      lrow[qf] = lrow[qf] * alpha + sum;

      int qrow = qf * 16 + l15;
      char* prow = Pw + qrow * 128;
#pragma unroll
      for (int kf = 0; kf < 4; ++kf) {
        unsigned off = kf * 32 + g * 8;
        off = (off & 15u) | ((((off >> 4) ^ (unsigned)qrow) & 7u) << 4);
        uint2 w;
        w.x = pack2(st[qf][kf][0], st[qf][kf][1]);
        w.y = pack2(st[qf][kf][2], st[qf][kf][3]);
        *(uint2*)(prow + off) = w;
      }
#pragma unroll
      for (int j = 0; j < 4; ++j) {
        float aj = __shfl(alpha, g * 4 + j);
#pragma unroll
        for (int df = 0; df < 4; ++df) o[qf][df][j] *= aj;
      }
    }

    // O += P @ V
#pragma unroll
    for (int kk = 0; kk < 2; ++kk) {
      bf16x8 vb[4];
#pragma unroll
      for (int df = 0; df < 4; ++df) {
        int r = df * 16 + l15;
        vb[df] = *(const bf16x8*)(Vs + r * 128 + (((kk * 4 + g) ^ (r & 7)) * 16));
      }
#pragma unroll
      for (int qf = 0; qf < 2; ++qf) {
        int qrow = qf * 16 + l15;
        bf16x8 pa = *(const bf16x8*)(Pw + qrow * 128 + ((((kk * 4 + g) ^ qrow) & 7) << 4));
#pragma unroll
        for (int df = 0; df < 4; ++df)
          o[qf][df] = __builtin_amdgcn_mfma_f32_16x16x32_bf16(pa, vb[df], o[qf][df], 0, 0, 0);
      }
    }
    __syncthreads();
  }

  const int b_idx = bh / 12, h = bh - b_idx * 12;
#pragma unroll
  for (int qf = 0; qf < 2; ++qf) {
    float linv = 1.0f / lrow[qf];
#pragma unroll
    for (int j = 0; j < 4; ++j) {
      float lj = __shfl(linv, g * 4 + j);
      int qrow = qbase + qf * 16 + g * 4 + j;
#pragma unroll
      for (int df = 0; df < 4; ++df) {
        int col = h * 64 + df * 16 + l15;
        Ao[(size_t)(b_idx * 1024 + qrow) * 768 + col] = f2bf(o[qf][df][j] * lj);
      }
    }
  }
}

// ---------------------------------------------------------------- launch

extern "C" void kernel_launch(void* const* d_in, const int* in_sizes, int n_in,
                              void* d_out, int out_size, void* d_ws, size_t ws_size,
                              hipStream_t stream) {
  const float* x     = (const float*)d_in[0];
  const float* w_qkv = (const float*)d_in[1];
  const float* w_out = (const float*)d_in[2];
  const float* b_out = (const float*)d_in[3];

  char* ws = (char*)d_ws;
  size_t off = 0;
  auto alloc = [&](size_t bytes) {
    void* p = ws + off;
    off += (bytes + 255) & ~(size_t)255;
    return p;
  };
  unsigned short* xb    = (unsigned short*)alloc(8192ull * 768 * 2);
  unsigned short* wqkvT = (unsigned short*)alloc(2304ull * 768 * 2);
  unsigned short* woutT = (unsigned short*)alloc(768ull * 768 * 2);
  unsigned short* Qb    = (unsigned short*)alloc(96ull * 1024 * 64 * 2);
  unsigned short* Kbf   = (unsigned short*)alloc(96ull * 1024 * 64 * 2);
  unsigned short* Vb    = (unsigned short*)alloc(96ull * 1024 * 64 * 2);
  unsigned short* VTb   = (unsigned short*)alloc(96ull * 1024 * 64 * 2);
  unsigned short* Aob   = (unsigned short*)alloc(96ull * 1024 * 64 * 2);

  k_cvt_bf16<<<3072, 256, 0, stream>>>(x, xb, 786432);
  k_transpose_w<<<dim3(36, 12), 256, 0, stream>>>(w_qkv, wqkvT, 768, 2304);
  k_transpose_w<<<dim3(12, 12), 256, 0, stream>>>(w_out, woutT, 768, 768);
  k_gemm<0><<<dim3(18, 64), 256, 0, stream>>>(xb, wqkvT, Qb, Kbf, Vb, nullptr);
  k_transpose_v<<<1536, 256, 0, stream>>>(Vb, VTb);
  k_attn<<<768, 256, 0, stream>>>(Qb, Kbf, VTb, Aob);
  k_gemm<1><<<dim3(6, 64), 256, 0, stream>>>(Aob, woutT, d_out, nullptr, nullptr, b_out);
}